// Round 3
// baseline (390.749 us; speedup 1.0000x reference)
//
#include <hip/hip_runtime.h>

#define NBATCH 4
#define NN 2048
#define NR 8192            // NBATCH*NN rows
#define TOPK 10

typedef __attribute__((ext_vector_type(4))) float f32x4;
typedef __attribute__((ext_vector_type(8))) short bf16x8;

__device__ inline unsigned short f2bf(float x) {
    unsigned u = __float_as_uint(x);
    unsigned r = (u + 0x7FFF + ((u >> 16) & 1)) >> 16;
    return (unsigned short)r;
}
__device__ inline float bf2f(unsigned short u) {
    return __uint_as_float(((unsigned)u) << 16);
}
__device__ inline unsigned long long shfl_xor_u64(unsigned long long x, int d) {
    unsigned lo = (unsigned)x, hi = (unsigned)(x >> 32);
    lo = __shfl_xor(lo, d); hi = __shfl_xor(hi, d);
    return ((unsigned long long)hi << 32) | lo;
}

// ---------------- K1: encoders + fusion + q/k projection (bf16, K=32 padded)
__global__ __launch_bounds__(256) void k1_encode(
    const float* __restrict__ xd, const float* __restrict__ xs,
    const float* __restrict__ Wd, const float* __restrict__ bd,
    const float* __restrict__ Ws, const float* __restrict__ bs,
    const float* __restrict__ Wf, const float* __restrict__ bf,
    const float* __restrict__ Wq, const float* __restrict__ Wk,
    unsigned short* __restrict__ qh, unsigned short* __restrict__ kh)
{
    int wave = threadIdx.x >> 6;
    int lane = threadIdx.x & 63;
    int r = blockIdx.x * 4 + wave;        // 0..8191

    __shared__ float xm[4][16];
    __shared__ float xst[4][8];
    __shared__ float hc[4][128];
    __shared__ float hh[4][64];

    const float* xdr = xd + (size_t)r * 512;
    float acc = 0.f;
    #pragma unroll
    for (int j = 0; j < 8; ++j) acc += xdr[lane + 64*j];
    acc += __shfl_xor(acc, 16);
    acc += __shfl_xor(acc, 32);
    if (lane < 16) xm[wave][lane] = acc * (1.0f/32.0f);
    if (lane < 8)  xst[wave][lane] = xs[(size_t)r*8 + lane];
    __syncthreads();

    float a1 = bd[lane];
    #pragma unroll
    for (int d = 0; d < 16; ++d) a1 += xm[wave][d] * Wd[d*64 + lane];
    a1 = fmaxf(a1, 0.f);
    float a2 = bs[lane];
    #pragma unroll
    for (int d = 0; d < 8; ++d) a2 += xst[wave][d] * Ws[d*64 + lane];
    a2 = fmaxf(a2, 0.f);
    hc[wave][lane] = a1;
    hc[wave][64 + lane] = a2;
    __syncthreads();

    float hv = bf[lane];
    #pragma unroll
    for (int j = 0; j < 128; ++j) hv += hc[wave][j] * Wf[j*64 + lane];
    hh[wave][lane] = hv;
    __syncthreads();

    float qv = 0.f, kv = 0.f;
    #pragma unroll
    for (int j = 0; j < 64; ++j) {
        float hj = hh[wave][j];
        qv += hj * Wq[j*64 + lane];
        kv += hj * Wk[j*64 + lane];
    }
    int b = r >> 11, n = r & 2047;
    int head = lane >> 4, dim = lane & 15;
    size_t base = ((size_t)(b*4 + head) * NN + n) * 32;
    qh[base + dim] = f2bf(qv);
    qh[base + 16 + dim] = 0;
    kh[base + dim] = f2bf(kv);
    kh[base + 16 + dim] = 0;
}

// ---------------- K2A: per-(b,h,row) softmax stats, single online sweep -----
__global__ __launch_bounds__(256) void k2A_stats(
    const unsigned short* __restrict__ qh, const unsigned short* __restrict__ kh,
    float* __restrict__ Mf, float* __restrict__ Rf)
{
    const float C1 = 0.36067376022224085f;   // 0.25 * log2(e)  (acc units -> log2)
    int bh = blockIdx.x >> 7;                // 16 (b,h) pairs
    int rg = blockIdx.x & 127;               // row group of 16
    int w = threadIdx.x >> 6, l = threadIdx.x & 63;
    int quad = l >> 4, lo = l & 15;

    bf16x8 afrag = *(const bf16x8*)(qh + ((size_t)bh * NN + rg*16 + lo) * 32 + quad*8);
    const unsigned short* kbase = kh + (size_t)bh * NN * 32;

    __shared__ float redM[4][16];
    __shared__ float redS[4][16];

    float M[4] = {-3e38f,-3e38f,-3e38f,-3e38f};
    float S[4] = {0.f,0.f,0.f,0.f};
    for (int t = 0; t < 32; ++t) {
        int m0 = w*512 + t*16;
        bf16x8 bfrag = *(const bf16x8*)(kbase + (size_t)(m0 + lo) * 32 + quad*8);
        f32x4 acc = {0.f,0.f,0.f,0.f};
        acc = __builtin_amdgcn_mfma_f32_16x16x32_bf16(afrag, bfrag, acc, 0, 0, 0);
        #pragma unroll
        for (int rr = 0; rr < 4; ++rr) {
            float nM = fmaxf(M[rr], acc[rr]);
            S[rr] = S[rr] * exp2f((M[rr] - nM) * C1) + exp2f((acc[rr] - nM) * C1);
            M[rr] = nM;
        }
    }
    // merge across the 16 lanes (lo) sharing each row
    #pragma unroll
    for (int d = 1; d <= 8; d <<= 1) {
        #pragma unroll
        for (int rr = 0; rr < 4; ++rr) {
            float oM = __shfl_xor(M[rr], d);
            float oS = __shfl_xor(S[rr], d);
            float nM = fmaxf(M[rr], oM);
            S[rr] = S[rr] * exp2f((M[rr] - nM) * C1) + oS * exp2f((oM - nM) * C1);
            M[rr] = nM;
        }
    }
    if (lo == 0) {
        #pragma unroll
        for (int rr = 0; rr < 4; ++rr) {
            redM[w][quad*4 + rr] = M[rr];
            redS[w][quad*4 + rr] = S[rr];
        }
    }
    __syncthreads();
    if (threadIdx.x < 16) {
        float nM = fmaxf(fmaxf(redM[0][threadIdx.x], redM[1][threadIdx.x]),
                         fmaxf(redM[2][threadIdx.x], redM[3][threadIdx.x]));
        float Sm = 0.f;
        #pragma unroll
        for (int ww = 0; ww < 4; ++ww)
            Sm += redS[ww][threadIdx.x] * exp2f((redM[ww][threadIdx.x] - nM) * C1);
        int row = rg*16 + threadIdx.x;
        Mf[(size_t)bh * NN + row] = 0.25f * nM;
        Rf[(size_t)bh * NN + row] = 1.0f / Sm;
    }
}

// ---------------- K2C: head-averaged values via MFMA + exact top-10 ---------
__global__ __launch_bounds__(256) void k2C_topk(
    const unsigned short* __restrict__ qh, const unsigned short* __restrict__ kh,
    const float* __restrict__ Mf, const float* __restrict__ Rf,
    float* __restrict__ fV, int* __restrict__ fI)
{
    const float C1 = 0.36067376022224085f;   // 0.25 * log2(e)
    const float L2E = 1.4426950408889634f;
    int b  = blockIdx.x >> 7;
    int rg = blockIdx.x & 127;
    int w = threadIdx.x >> 6, l = threadIdx.x & 63;
    int quad = l >> 4, lo = l & 15;

    __shared__ unsigned short vt[16][2048];  // bf16 values, XOR-swizzled cols

    bf16x8 afrag[4];
    float b2[4][4], r4[4][4];
    #pragma unroll
    for (int h = 0; h < 4; ++h) {
        int bh = b*4 + h;
        afrag[h] = *(const bf16x8*)(qh + ((size_t)bh * NN + rg*16 + lo) * 32 + quad*8);
        #pragma unroll
        for (int rr = 0; rr < 4; ++rr) {
            int row = rg*16 + quad*4 + rr;
            b2[h][rr] = Mf[(size_t)bh * NN + row] * L2E;
            r4[h][rr] = Rf[(size_t)bh * NN + row] * 0.25f;
        }
    }

    int swz_w = quad << 4;                   // write swizzle = (row>>2)*16
    for (int t = 0; t < 32; ++t) {
        int m0 = w*512 + t*16;
        float vacc[4] = {0.f,0.f,0.f,0.f};
        #pragma unroll
        for (int h = 0; h < 4; ++h) {
            bf16x8 bfrag = *(const bf16x8*)(kh + ((size_t)(b*4+h) * NN + m0 + lo) * 32 + quad*8);
            f32x4 acc = {0.f,0.f,0.f,0.f};
            acc = __builtin_amdgcn_mfma_f32_16x16x32_bf16(afrag[h], bfrag, acc, 0, 0, 0);
            #pragma unroll
            for (int rr = 0; rr < 4; ++rr) {
                float e = exp2f(fmaf(acc[rr], C1, -b2[h][rr]));
                vacc[rr] = fmaf(e, r4[h][rr], vacc[rr]);
            }
        }
        #pragma unroll
        for (int rr = 0; rr < 4; ++rr)
            vt[quad*4 + rr][(m0 + lo) ^ swz_w] = f2bf(vacc[rr]);
    }
    __syncthreads();

    for (int rr = 0; rr < 4; ++rr) {
        int row = w*4 + rr;
        int swz = (row >> 2) << 4;
        float tv[TOPK]; int ti[TOPK];
        #pragma unroll
        for (int s = 0; s < TOPK; ++s) { tv[s] = -3e38f; ti[s] = 0; }
        for (int j = 0; j < 16; ++j) {
            int m1 = 2*l + 128*j;
            unsigned pair = *(const unsigned*)&vt[row][m1 ^ swz];
            #pragma unroll
            for (int half = 0; half < 2; ++half) {
                float v = bf2f((unsigned short)(half ? (pair >> 16) : (pair & 0xFFFF)));
                int m = m1 + half;
                if (v > tv[TOPK-1]) {
                    float cv = v; int ci = m;
                    #pragma unroll
                    for (int s = 0; s < TOPK; ++s) {
                        bool ins = cv > tv[s];
                        float ov = tv[s]; int oi = ti[s];
                        tv[s] = ins ? cv : ov;  ti[s] = ins ? ci : oi;
                        cv    = ins ? ov : cv;  ci    = ins ? oi : ci;
                    }
                }
            }
        }
        int rowg = b * NN + rg*16 + row;
        #pragma unroll 1
        for (int s = 0; s < TOPK; ++s) {
            unsigned vb = __float_as_uint(fmaxf(tv[0], 0.0f));
            unsigned long long key =
                ((unsigned long long)vb << 12) | (unsigned)(2047 - ti[0]);
            unsigned long long kmax = key;
            #pragma unroll
            for (int d = 1; d < 64; d <<= 1) {
                unsigned long long o = shfl_xor_u64(kmax, d);
                kmax = (o > kmax) ? o : kmax;
            }
            if (key == kmax) {
                #pragma unroll
                for (int q = 0; q < TOPK-1; ++q) { tv[q] = tv[q+1]; ti[q] = ti[q+1]; }
                tv[TOPK-1] = -3e38f; ti[TOPK-1] = 0;
            }
            if (l == 0) {
                fV[(size_t)s * NR + rowg] = __uint_as_float((unsigned)(kmax >> 12));
                fI[(size_t)s * NR + rowg] = 2047 - (int)(kmax & 0xFFF);
            }
        }
    }
}

// ---------------- E0: clear incoming-edge counters --------------------------
__global__ __launch_bounds__(256) void e0_clear(int* __restrict__ cnt)
{
    cnt[blockIdx.x * 256 + threadIdx.x] = 0;
}

// ---------------- E1: count incoming edges per column -----------------------
__global__ __launch_bounds__(256) void e1_count(
    const int* __restrict__ fI, int* __restrict__ cnt)
{
    int idx = blockIdx.x * 256 + threadIdx.x;      // 0..81919
    int r = idx & (NR - 1);
    int s = idx >> 13;
    int b = r >> 11;
    int j = fI[(size_t)s * NR + r];
    atomicAdd(&cnt[b * NN + j], 1);
}

// ---------------- E2: exclusive scan of 8192 counts (single block) ----------
__global__ __launch_bounds__(1024) void e2_scan(
    const int* __restrict__ cnt, int* __restrict__ off, int* __restrict__ cur)
{
    __shared__ int part[1024];
    int t = threadIdx.x;
    int c[8];
    int s = 0;
    #pragma unroll
    for (int i = 0; i < 8; ++i) { c[i] = cnt[t*8 + i]; s += c[i]; }
    part[t] = s;
    __syncthreads();
    for (int d = 1; d < 1024; d <<= 1) {
        int v = (t >= d) ? part[t - d] : 0;
        __syncthreads();
        part[t] += v;
        __syncthreads();
    }
    int excl = (t == 0) ? 0 : part[t - 1];
    #pragma unroll
    for (int i = 0; i < 8; ++i) {
        off[t*8 + i] = excl;
        cur[t*8 + i] = excl;
        excl += c[i];
    }
    if (t == 1023) off[8192] = excl;
}

// ---------------- E3: fill incoming CSR lists -------------------------------
__global__ __launch_bounds__(256) void e3_fill(
    const float* __restrict__ fV, const int* __restrict__ fI,
    int* __restrict__ cur, int* __restrict__ inc_src, float* __restrict__ inc_val)
{
    int idx = blockIdx.x * 256 + threadIdx.x;
    int r = idx & (NR - 1);
    int s = idx >> 13;
    int b = r >> 11, n = r & 2047;
    int j = fI[(size_t)s * NR + r];
    float v = fV[(size_t)s * NR + r];
    int pos = atomicAdd(&cur[b * NN + j], 1);
    inc_src[pos] = n;
    inc_val[pos] = 0.35f * v;
}

// ---------------- E4: fused epilogue: row = 0.3*prior + sparse sym; A,L,diag -
__global__ __launch_bounds__(256) void e4_final(
    const float* __restrict__ prior,
    const float* __restrict__ fV, const int* __restrict__ fI,
    const int* __restrict__ off, const int* __restrict__ inc_src,
    const float* __restrict__ inc_val,
    float* __restrict__ Lout, float* __restrict__ Aout)
{
    int r = blockIdx.x;                      // global row 0..8191
    int n = r & 2047;
    int tid = threadIdx.x;

    __shared__ float srow[2048];
    __shared__ float wsum[4];

    const float4* pr = (const float4*)(prior + (size_t)r * NN);
    float4* sr4 = (float4*)srow;
    for (int i = tid; i < 512; i += 256) {
        float4 p = pr[i];
        float4 a; a.x = 0.3f*p.x; a.y = 0.3f*p.y; a.z = 0.3f*p.z; a.w = 0.3f*p.w;
        sr4[i] = a;
    }
    __syncthreads();

    if (tid < TOPK) {
        int j = fI[(size_t)tid * NR + r];
        float wv = 0.35f * fV[(size_t)tid * NR + r];
        atomicAdd(&srow[j], wv);
    }
    int beg = off[r], end = off[r + 1];
    for (int t = beg + tid; t < end; t += 256)
        atomicAdd(&srow[inc_src[t]], inc_val[t]);
    __syncthreads();

    float sum = 0.f;
    for (int i = tid; i < 512; i += 256) {
        float4 a = sr4[i];
        sum += a.x + a.y + a.z + a.w;
    }
    #pragma unroll
    for (int o = 32; o > 0; o >>= 1) sum += __shfl_down(sum, o);
    if ((tid & 63) == 0) wsum[tid >> 6] = sum;
    __syncthreads();
    float degv = wsum[0] + wsum[1] + wsum[2] + wsum[3];

    float4* Ar = (float4*)(Aout + (size_t)r * NN);
    float4* Lr = (float4*)(Lout + (size_t)r * NN);
    int dq = n >> 2, dc = n & 3;
    for (int i = tid; i < 512; i += 256) {
        float4 a = sr4[i];
        Ar[i] = a;
        float4 lv; lv.x = -a.x; lv.y = -a.y; lv.z = -a.z; lv.w = -a.w;
        if (i == dq) ((float*)&lv)[dc] += degv;
        Lr[i] = lv;
    }
}

extern "C" void kernel_launch(void* const* d_in, const int* in_sizes, int n_in,
                              void* d_out, int out_size, void* d_ws, size_t ws_size,
                              hipStream_t stream)
{
    const float* xd    = (const float*)d_in[0];
    const float* xs    = (const float*)d_in[1];
    const float* prior = (const float*)d_in[2];
    const float* Wd    = (const float*)d_in[3];
    const float* bd    = (const float*)d_in[4];
    const float* Ws    = (const float*)d_in[5];
    const float* bs    = (const float*)d_in[6];
    const float* Wf    = (const float*)d_in[7];
    const float* bf    = (const float*)d_in[8];
    const float* Wq    = (const float*)d_in[9];
    const float* Wk    = (const float*)d_in[10];

    float* Lout = (float*)d_out;
    float* Aout = Lout + (size_t)NR * NN;

    unsigned short* qh = (unsigned short*)d_ws;          // 16*2048*32 bf16 = 2MB
    unsigned short* kh = qh + (size_t)16 * NN * 32;      // 2MB
    float* Mf  = (float*)(kh + (size_t)16 * NN * 32);    // 128KB
    float* Rf  = Mf + (size_t)16 * NN;                   // 128KB
    float* fV  = Rf + (size_t)16 * NN;                   // 320KB
    int*   fI  = (int*)(fV + (size_t)TOPK * NR);         // 320KB
    int*   cnt = fI + (size_t)TOPK * NR;                 // 8192
    int*   off = cnt + NR;                               // 8193
    int*   cur = off + NR + 64;                          // 8192
    int*   inc_src = cur + NR;                           // 81920
    float* inc_val = (float*)(inc_src + (size_t)TOPK * NR);

    k1_encode<<<NR/4, 256, 0, stream>>>(xd, xs, Wd, bd, Ws, bs, Wf, bf, Wq, Wk, qh, kh);
    k2A_stats<<<16*128, 256, 0, stream>>>(qh, kh, Mf, Rf);
    k2C_topk<<<4*128, 256, 0, stream>>>(qh, kh, Mf, Rf, fV, fI);
    e0_clear<<<NR/256, 256, 0, stream>>>(cnt);
    e1_count<<<(NR*TOPK)/256, 256, 0, stream>>>(fI, cnt);
    e2_scan<<<1, 1024, 0, stream>>>(cnt, off, cur);
    e3_fill<<<(NR*TOPK)/256, 256, 0, stream>>>(fV, fI, cur, inc_src, inc_val);
    e4_final<<<NR, 256, 0, stream>>>(prior, fV, fI, off, inc_src, inc_val, Lout, Aout);
}